// Round 1
// baseline (1089.005 us; speedup 1.0000x reference)
//
#include <hip/hip_runtime.h>

// Fusedmax: out = sparsemax(prox_TV1D(x, alpha=1)) row-wise. B=4096, N=512, fp32.
//
// v2 design: LANE-PARALLEL TV. The previous version ran Condat's serial scan on
// lane 0 of a dedicated wave per row (1/64 lane efficiency, VALUBusy 51%,
// HBM 0.5% -> pure issue/latency bound). Now each block owns 16 rows and lanes
// 0..15 each run the Condat scan on their OWN row in lockstep, amortizing each
// wave64 instruction issue over 16 chains.
//
// LDS layout: column-interleaved buf[(i<<4)|m] (element i of local row m).
// Lane m's whole row maps to a single bank (bank = m or m+16 by parity of i),
// distinct per lane -> per-lane gathers and flush writes are conflict-free.
//
// TV runs IN PLACE (flush frontier trails the read frontier; the only re-read
// hazard is index N-1 in the end phase, handled by the yLast snapshot exactly
// as in the reference).

#define TVN 512
#define RPB 16          // rows per block, one per lane (lanes 0..15)
#define LAMBDA 1.0f

__device__ __forceinline__ float wave_reduce_sum(float v) {
#pragma unroll
    for (int off = 32; off > 0; off >>= 1) v += __shfl_xor(v, off, 64);
    return v;
}

__global__ __launch_bounds__(64) void fusedmax_kernel(const float* __restrict__ xin,
                                                      float* __restrict__ out) {
    __shared__ float buf[TVN * RPB];          // 32 KB, [i][m] column-interleaved
    const int t = threadIdx.x;                // 0..63
    const int m = t & (RPB - 1);              // local row this lane touches
    const int q = t >> 4;                     // row quarter staged by this lane
    const int r0 = blockIdx.x * RPB;

#define Y(i) buf[((i) << 4) | m]

    // ---- stage 16 rows: lane t loads 128 consecutive floats of row m via float4,
    //      scatters into the column layout (4-way write conflict max: t,t+16,t+32,t+48) ----
    {
        const float4* __restrict__ g4 = (const float4*)(xin + (r0 + m) * TVN + q * 128);
#pragma unroll 8
        for (int c = 0; c < 32; ++c) {
            float4 w = g4[c];
            const int i = q * 128 + c * 4;
            buf[((i + 0) << 4) | m] = w.x;
            buf[((i + 1) << 4) | m] = w.y;
            buf[((i + 2) << 4) | m] = w.z;
            buf[((i + 3) << 4) | m] = w.w;
        }
    }
    __syncthreads();

    // ---- Condat 1-D TV denoise: one row per lane, lanes 0..15, in place ----
    if (t < RPB) {
        const float lam = LAMBDA;
        const float twolam = 2.0f * lam;
        const float yLast = Y(TVN - 1);
        int k = 0, k0 = 0, km = 0, kp = 0;
        float vmin = Y(0) - lam, vmax = Y(0) + lam;
        float umin = lam, umax = -lam;
        for (;;) {
            if (k == TVN - 1) {
                if (umin < 0.0f) {                       // end-phase negative jump
                    for (int i = k0; i <= km; ++i) Y(i) = vmin;
                    int nk = km + 1;
                    float ynk = (nk > TVN - 1) ? yLast : Y(nk);
                    if (nk > TVN - 1) nk = TVN - 1;
                    k = k0 = km = nk;
                    vmin = ynk;
                    umin = lam;
                    umax = ynk + lam - vmax;             // old vmax
                } else if (umax > 0.0f) {                // end-phase positive jump
                    for (int i = k0; i <= kp; ++i) Y(i) = vmax;
                    int nk = kp + 1;
                    float ynk = (nk > TVN - 1) ? yLast : Y(nk);
                    if (nk > TVN - 1) nk = TVN - 1;
                    k = k0 = kp = nk;
                    vmax = ynk;
                    umax = -lam;
                    umin = ynk - lam - vmin;             // old vmin
                } else {                                  // finish
                    float v = vmin + umin / (float)(k - k0 + 1);
                    for (int i = k0; i < TVN; ++i) Y(i) = v;
                    break;
                }
            } else {
                float yn = Y(k + 1);
                if (yn + umin < vmin - lam) {            // negative jump
                    for (int i = k0; i <= km; ++i) Y(i) = vmin;
                    int nk = km + 1;                      // <= N-1, untouched index
                    float ynk = Y(nk);
                    k = k0 = km = kp = nk;
                    vmin = ynk;
                    vmax = ynk + twolam;
                    umin = lam;
                    umax = -lam;
                } else if (yn + umax > vmax + lam) {     // positive jump
                    for (int i = k0; i <= kp; ++i) Y(i) = vmax;
                    int nk = kp + 1;
                    float ynk = Y(nk);
                    k = k0 = km = kp = nk;
                    vmax = ynk;
                    vmin = ynk - twolam;
                    umin = lam;
                    umax = -lam;
                } else {                                  // accumulate
                    ++k;
                    umin += yn - vmin;
                    umax += yn - vmax;
                    if (umin >= lam) {
                        vmin += (umin - lam) / (float)(k - k0 + 1);
                        umin = lam;
                        km = k;
                    }
                    if (umax <= -lam) {
                        vmax += (umax + lam) / (float)(k - k0 + 1);
                        umax = -lam;
                        kp = k;
                    }
                }
            }
        }
    }
    __syncthreads();

    // ---- sparsemax: whole wave per row, 16 rows sequentially (Michelot fixed point) ----
    for (int mm = 0; mm < RPB; ++mm) {
        float v[8];
#pragma unroll
        for (int j = 0; j < 4; ++j) v[j] = buf[((4 * t + j) << 4) | mm];
#pragma unroll
        for (int j = 0; j < 4; ++j) v[4 + j] = buf[((256 + 4 * t + j) << 4) | mm];

        float ls = v[0] + v[1] + v[2] + v[3] + v[4] + v[5] + v[6] + v[7];
        float S = wave_reduce_sum(ls);
        float tau = (S - 1.0f) * (1.0f / (float)TVN);   // support = all
        int cprev = TVN;
#pragma unroll 1
        for (int it = 0; it < 64; ++it) {
            float s = 0.0f, c = 0.0f;
#pragma unroll
            for (int j = 0; j < 8; ++j) {
                if (v[j] > tau) { s += v[j]; c += 1.0f; }
            }
            s = wave_reduce_sum(s);
            c = wave_reduce_sum(c);               // >= 1 always (tau < max)
            tau = (s - 1.0f) / c;
            int ci = (int)c;
            if (ci == cprev) break;               // support stabilized -> tau exact
            cprev = ci;
        }

        float4 oa, ob;
        oa.x = fmaxf(v[0] - tau, 0.0f);
        oa.y = fmaxf(v[1] - tau, 0.0f);
        oa.z = fmaxf(v[2] - tau, 0.0f);
        oa.w = fmaxf(v[3] - tau, 0.0f);
        ob.x = fmaxf(v[4] - tau, 0.0f);
        ob.y = fmaxf(v[5] - tau, 0.0f);
        ob.z = fmaxf(v[6] - tau, 0.0f);
        ob.w = fmaxf(v[7] - tau, 0.0f);
        float4* __restrict__ o4 = (float4*)(out + (r0 + mm) * TVN);
        o4[t] = oa;                               // elements 4t..4t+3
        o4[t + 64] = ob;                          // elements 256+4t..256+4t+3
    }
}

extern "C" void kernel_launch(void* const* d_in, const int* in_sizes, int n_in,
                              void* d_out, int out_size, void* d_ws, size_t ws_size,
                              hipStream_t stream) {
    const float* x = (const float*)d_in[0];
    float* out = (float*)d_out;
    const int rows = in_sizes[0] / TVN;       // 4096
    fusedmax_kernel<<<dim3(rows / RPB), dim3(64), 0, stream>>>(x, out);
}

// Round 2
// 262.519 us; speedup vs baseline: 4.1483x; 4.1483x over previous
//
#include <hip/hip_runtime.h>

// Fusedmax: out = sparsemax(prox_TV1D(x, alpha=1)) row-wise. B=4096, N=512, fp32.
//
// v3: back to the v1 mapping (one wave per row, lane 0 runs Condat's scan) --
// v2 proved that lane-packing chains kills occupancy (256 waves = 1/CU, LDS
// latency fully exposed, 3.2x regression). With c=1 the kernel is issue+latency
// bound on the serial chain, so v3 shortens the chain step:
//   (a) batch-of-8 register lookahead: prefetch row[k+1..k+8] into named
//       registers once per 8 accumulate steps (dependent ds_read every 8 steps
//       instead of every step; jumps just discard the prefetch and refill).
//   (b) v_rcp_f32 * (umin-lam) instead of IEEE divide in the clamp updates
//       (clamps fire ~every step for lam=1 on N(0,1); IEEE div is ~10 inst +
//       long dependent chain). Count maintained incrementally as float.
// In-place safety: prefetch reads indices >= k+1; flushes write <= k. An 8-float
// zero pad past N makes over-reads safe (values never consumed).
// Staging, end phase, sparsemax identical to the 331us v1 kernel.

#define TVN 512
#define LAMBDA 1.0f

__device__ __forceinline__ float wave_reduce_sum(float v) {
#pragma unroll
    for (int off = 32; off > 0; off >>= 1) v += __shfl_xor(v, off, 64);
    return v;
}

__global__ __launch_bounds__(64) void fusedmax_kernel(const float* __restrict__ xin,
                                                      float* __restrict__ out) {
    __shared__ alignas(16) float row[TVN + 8];
    const int t = threadIdx.x;                 // 0..63
    const long long r = blockIdx.x;
    const float lam = LAMBDA;

    // ---- stage row into LDS, coalesced (16B/lane) ----
    const float4* __restrict__ g4 = (const float4*)(xin + r * TVN);
    float4* s4 = (float4*)row;
    s4[t] = g4[t];
    s4[t + 64] = g4[t + 64];
    if (t < 8) row[TVN + t] = 0.0f;            // prefetch pad (never consumed)
    __syncthreads();

    // ---- Condat 1-D TV denoise, serial on lane 0, in place ----
    if (t == 0) {
        const float yLast = row[TVN - 1];
        const float twolam = 2.0f * lam;
        int k = 0, k0 = 0, km = 0, kp = 0;
        float vmin = row[0] - lam, vmax = row[0] + lam;
        float umin = lam, umax = -lam;
        float cntf = 1.0f;                     // == (float)(k - k0 + 1)
        float yn;

#define ACCUM_STEP(W)                                                   \
        yn = (W);                                                       \
        if (yn + umin < vmin - lam) goto neg_jump;                      \
        if (yn + umax > vmax + lam) goto pos_jump;                      \
        ++k; cntf += 1.0f;                                              \
        umin += yn - vmin;                                              \
        umax += yn - vmax;                                              \
        if (umin >= lam) {                                              \
            vmin += (umin - lam) * __builtin_amdgcn_rcpf(cntf);         \
            umin = lam; km = k;                                         \
        }                                                               \
        if (umax <= -lam) {                                             \
            vmax += (umax + lam) * __builtin_amdgcn_rcpf(cntf);         \
            umax = -lam; kp = k;                                        \
        }                                                               \
        if (k == TVN - 1) goto end_phase;

    refill: {
            // k <= TVN-2 here: up to 8 accumulate steps from registers
            float w0 = row[k + 1], w1 = row[k + 2], w2 = row[k + 3], w3 = row[k + 4];
            float w4 = row[k + 5], w5 = row[k + 6], w6 = row[k + 7], w7 = row[k + 8];
            ACCUM_STEP(w0)
            ACCUM_STEP(w1)
            ACCUM_STEP(w2)
            ACCUM_STEP(w3)
            ACCUM_STEP(w4)
            ACCUM_STEP(w5)
            ACCUM_STEP(w6)
            ACCUM_STEP(w7)
            goto refill;
        }
#undef ACCUM_STEP

    neg_jump: {
            for (int i = k0; i <= km; ++i) row[i] = vmin;
            const int nk = km + 1;             // <= TVN-1, untouched index
            const float ynk = row[nk];
            k = k0 = km = kp = nk;
            vmin = ynk;
            vmax = ynk + twolam;
            umin = lam;
            umax = -lam;
            cntf = 1.0f;
            if (k == TVN - 1) goto end_phase;
            goto refill;
        }

    pos_jump: {
            for (int i = k0; i <= kp; ++i) row[i] = vmax;
            const int nk = kp + 1;
            const float ynk = row[nk];
            k = k0 = km = kp = nk;
            vmax = ynk;
            vmin = ynk - twolam;
            umin = lam;
            umax = -lam;
            cntf = 1.0f;
            if (k == TVN - 1) goto end_phase;
            goto refill;
        }

    end_phase: {
            if (umin < 0.0f) {                 // end-phase negative jump
                for (int i = k0; i <= km; ++i) row[i] = vmin;
                int nk = km + 1;
                const float ynk = (nk > TVN - 1) ? yLast : row[nk];
                if (nk > TVN - 1) nk = TVN - 1;
                k = k0 = km = nk;
                vmin = ynk;
                umin = lam;
                umax = ynk + lam - vmax;       // old vmax
                cntf = 1.0f;
                if (k == TVN - 1) goto end_phase;
                goto refill;
            } else if (umax > 0.0f) {          // end-phase positive jump
                for (int i = k0; i <= kp; ++i) row[i] = vmax;
                int nk = kp + 1;
                const float ynk = (nk > TVN - 1) ? yLast : row[nk];
                if (nk > TVN - 1) nk = TVN - 1;
                k = k0 = kp = nk;
                vmax = ynk;
                umax = -lam;
                umin = ynk - lam - vmin;       // old vmin
                cntf = 1.0f;
                if (k == TVN - 1) goto end_phase;
                goto refill;
            } else {                           // finish
                const float v = vmin + umin / (float)(k - k0 + 1);
                for (int i = k0; i < TVN; ++i) row[i] = v;
            }
        }
    }
    __syncthreads();

    // ---- sparsemax via Michelot fixed point (exact tau, no sort) ----
    float4 a = s4[t];
    float4 b = s4[t + 64];
    float v[8] = {a.x, a.y, a.z, a.w, b.x, b.y, b.z, b.w};

    float ls = v[0] + v[1] + v[2] + v[3] + v[4] + v[5] + v[6] + v[7];
    float S = wave_reduce_sum(ls);
    float tau = (S - 1.0f) * (1.0f / (float)TVN);   // support = all
    int cprev = TVN;
#pragma unroll 1
    for (int it = 0; it < 64; ++it) {
        float s = 0.0f, c = 0.0f;
#pragma unroll
        for (int j = 0; j < 8; ++j) {
            if (v[j] > tau) { s += v[j]; c += 1.0f; }
        }
        s = wave_reduce_sum(s);
        c = wave_reduce_sum(c);               // >= 1 always (tau < max)
        tau = (s - 1.0f) / c;
        int ci = (int)c;
        if (ci == cprev) break;               // support stabilized -> tau exact
        cprev = ci;
    }

    float4 oa, ob;
    oa.x = fmaxf(v[0] - tau, 0.0f);
    oa.y = fmaxf(v[1] - tau, 0.0f);
    oa.z = fmaxf(v[2] - tau, 0.0f);
    oa.w = fmaxf(v[3] - tau, 0.0f);
    ob.x = fmaxf(v[4] - tau, 0.0f);
    ob.y = fmaxf(v[5] - tau, 0.0f);
    ob.z = fmaxf(v[6] - tau, 0.0f);
    ob.w = fmaxf(v[7] - tau, 0.0f);
    float4* __restrict__ o4 = (float4*)(out + r * TVN);
    o4[t] = oa;
    o4[t + 64] = ob;
}

extern "C" void kernel_launch(void* const* d_in, const int* in_sizes, int n_in,
                              void* d_out, int out_size, void* d_ws, size_t ws_size,
                              hipStream_t stream) {
    const float* x = (const float*)d_in[0];
    float* out = (float*)d_out;
    const int rows = in_sizes[0] / TVN;       // 4096
    fusedmax_kernel<<<dim3(rows), dim3(64), 0, stream>>>(x, out);
}